// Round 7
// baseline (62.650 us; speedup 1.0000x reference)
//
#include <hip/hip_runtime.h>
#include <math.h>

#define BATCH 64
#define SEQ   4096
#define HID   256
#define NBLK  32                          // S-chunks per batch
#define ROWS_PER_BLK (SEQ / NBLK)         // 128 rows per block
#define THREADS 256
#define NWAVE (THREADS / 64)              // 4 waves
#define GSZ   32                          // lanes per row-group (half-wave)
#define NGRP  (THREADS / GSZ)             // 8 groups -> 8 rows per iter
#define ITERS (ROWS_PER_BLK / NGRP)       // 16 serial iterations (even)
#define VPL   (HID / (GSZ * 4))           // 2 float4 per lane per row

// Kernel 1: single streaming pass over trg with online softmax (defer-max).
// Each 32-lane half-wave owns one row per iteration (2 float4/lane -> tiny
// live set, target <=64 VGPR = 8 waves/SIMD = 32 waves/CU for max loads in
// flight). Manual 2-stage prefetch (static names). Cross-group combine is a
// single xor-32 shuffle; LDS only for the 4-wave combine (4.2 KB).
__global__ __launch_bounds__(THREADS, 8) void pool_pass(
        const float* __restrict__ trg,
        float* __restrict__ ws_m,
        float* __restrict__ ws_l,
        float* __restrict__ ws_p) {
    const int b     = blockIdx.x / NBLK;
    const int chunk = blockIdx.x % NBLK;
    const int tid   = threadIdx.x;
    const int wave  = tid >> 6;
    const int lane  = tid & 63;
    const int gid   = tid >> 5;           // block-level group id 0..7
    const int sub   = tid & 31;           // lane within group
    const int gw    = lane >> 5;          // group id within wave 0..1

    const float* base = trg + ((size_t)b * SEQ + (size_t)chunk * ROWS_PER_BLK) * HID
                      + (size_t)gid * HID + sub * 4;   // row gid, this lane's cols

    float m = -INFINITY, l = 0.f;
    float4 acc[VPL];
    #pragma unroll
    for (int q = 0; q < VPL; ++q) acc[q] = make_float4(0.f, 0.f, 0.f, 0.f);

    float4 v0[VPL], v1[VPL];

    #define LOADV(dst, t)                                                     \
        {                                                                     \
            const float* rp_ = base + (size_t)(t) * (NGRP * HID);             \
            _Pragma("unroll")                                                 \
            for (int q = 0; q < VPL; ++q)                                     \
                dst[q] = *reinterpret_cast<const float4*>(rp_ + q * (GSZ*4)); \
        }

    #define PROCESS(v)                                                        \
        {                                                                     \
            float ss = 0.f;                                                   \
            _Pragma("unroll")                                                 \
            for (int q = 0; q < VPL; ++q)                                     \
                ss += v[q].x * v[q].x + v[q].y * v[q].y                       \
                    + v[q].z * v[q].z + v[q].w * v[q].w;                      \
            ss += __shfl_xor(ss, 1, 64);                                      \
            ss += __shfl_xor(ss, 2, 64);                                      \
            ss += __shfl_xor(ss, 4, 64);                                      \
            ss += __shfl_xor(ss, 8, 64);                                      \
            ss += __shfl_xor(ss, 16, 64);                                     \
            const float nrm = sqrtf(ss);                                      \
            if (nrm > m + 8.f) {          /* defer-max: rare */               \
                const float sc_ = __expf(m - nrm);                            \
                l *= sc_;                                                     \
                _Pragma("unroll")                                             \
                for (int q = 0; q < VPL; ++q) {                               \
                    acc[q].x *= sc_; acc[q].y *= sc_;                         \
                    acc[q].z *= sc_; acc[q].w *= sc_;                         \
                }                                                             \
                m = nrm;                                                      \
            }                                                                 \
            const float p = __expf(nrm - m);   /* <= e^8 */                   \
            l += p;                                                           \
            _Pragma("unroll")                                                 \
            for (int q = 0; q < VPL; ++q) {                                   \
                acc[q].x = fmaf(p, v[q].x, acc[q].x);                         \
                acc[q].y = fmaf(p, v[q].y, acc[q].y);                         \
                acc[q].z = fmaf(p, v[q].z, acc[q].z);                         \
                acc[q].w = fmaf(p, v[q].w, acc[q].w);                         \
            }                                                                 \
        }

    LOADV(v0, 0)
    #pragma unroll 1                      // control codegen/regs; ping-pong
    for (int t = 0; t < ITERS; t += 2) {
        LOADV(v1, t + 1)                  // prefetch while v0 computes
        PROCESS(v0)
        if (t + 2 < ITERS) LOADV(v0, t + 2)
        PROCESS(v1)
    }
    #undef LOADV
    #undef PROCESS

    // ---- in-wave cross-group combine (xor 32 crosses the 2 half-waves) ----
    const float m_w = fmaxf(m, __shfl_xor(m, 32, 64));
    const float sc  = __expf(m - m_w);    // group-uniform rescale to wave max
    float l_w = l * sc;
    l_w += __shfl_xor(l_w, 32, 64);
    #pragma unroll
    for (int q = 0; q < VPL; ++q) {
        float4 a = acc[q];
        a.x *= sc; a.y *= sc; a.z *= sc; a.w *= sc;
        a.x += __shfl_xor(a.x, 32, 64);
        a.y += __shfl_xor(a.y, 32, 64);
        a.z += __shfl_xor(a.z, 32, 64);
        a.w += __shfl_xor(a.w, 32, 64);
        acc[q] = a;                       // wave col-sums for cols q*128+sub*4
    }

    // lane (gw,sub) keeps cols gw*128 + sub*4 .. +3 (static select, no scratch)
    const float4 mine = gw ? acc[1] : acc[0];

    // ---- tiny cross-wave combine in LDS (4.2 KB) ----
    __shared__ float s_p[NWAVE][HID];
    __shared__ float s_m[NWAVE];
    __shared__ float s_l[NWAVE];
    *reinterpret_cast<float4*>(&s_p[wave][gw * 128 + sub * 4]) = mine;
    if (lane == 0) { s_m[wave] = m_w; s_l[wave] = l_w; }
    __syncthreads();

    const int j = tid;                    // output column 0..255
    const float m_blk = fmaxf(fmaxf(s_m[0], s_m[1]), fmaxf(s_m[2], s_m[3]));
    const float e0 = __expf(s_m[0] - m_blk);
    const float e1 = __expf(s_m[1] - m_blk);
    const float e2 = __expf(s_m[2] - m_blk);
    const float e3 = __expf(s_m[3] - m_blk);
    const float pj = e0 * s_p[0][j] + e1 * s_p[1][j]
                   + e2 * s_p[2][j] + e3 * s_p[3][j];
    const int pidx = b * NBLK + chunk;
    ws_p[(size_t)pidx * HID + j] = pj;
    if (j == 0) {
        ws_m[pidx] = m_blk;
        ws_l[pidx] = e0 * s_l[0] + e1 * s_l[1] + e2 * s_l[2] + e3 * s_l[3];
    }
}

// Kernel 2: combine NBLK partials per batch, normalize, tiny MLP.
__global__ __launch_bounds__(THREADS) void finish_pass(
        const float* __restrict__ ws_m,
        const float* __restrict__ ws_l,
        const float* __restrict__ ws_p,
        const float* __restrict__ W1,
        const float* __restrict__ b1,
        const float* __restrict__ W2,
        const float* __restrict__ b2,
        float* __restrict__ out) {
    const int b = blockIdx.x;
    const int j = threadIdx.x;  // 0..255: owns pooled[j], h[j]

    __shared__ float s_m[NBLK];
    __shared__ float s_l[NBLK];
    __shared__ float s_scale[NBLK];
    __shared__ float s_pooled[HID];
    __shared__ float s_red[NWAVE];

    if (j < NBLK) {
        s_m[j] = ws_m[b * NBLK + j];
        s_l[j] = ws_l[b * NBLK + j];
    }
    __syncthreads();

    float m = s_m[0];
    #pragma unroll
    for (int i = 1; i < NBLK; ++i) m = fmaxf(m, s_m[i]);
    if (j < NBLK) s_scale[j] = __expf(s_m[j] - m);
    __syncthreads();

    float l = 0.f, pj = 0.f;
    #pragma unroll 8
    for (int i = 0; i < NBLK; ++i) {
        l  = fmaf(s_l[i], s_scale[i], l);
        pj = fmaf(ws_p[(size_t)(b * NBLK + i) * HID + j], s_scale[i], pj);
    }
    s_pooled[j] = pj / l;
    __syncthreads();

    // FC1 column j: h = relu(sum_k pooled[k] * W1[k][j] + b1[j])
    float h = b1[j];
    #pragma unroll 16
    for (int k = 0; k < HID; ++k)
        h = fmaf(s_pooled[k], W1[k * HID + j], h);
    h = fmaxf(h, 0.f);

    // FC2: out[b] = sum_j h[j] * W2[j] + b2
    float v = h * W2[j];
    #pragma unroll
    for (int off = 32; off > 0; off >>= 1)
        v += __shfl_xor(v, off, 64);
    if ((j & 63) == 0) s_red[j >> 6] = v;
    __syncthreads();
    if (j == 0)
        out[b] = s_red[0] + s_red[1] + s_red[2] + s_red[3] + b2[0];
}

extern "C" void kernel_launch(void* const* d_in, const int* in_sizes, int n_in,
                              void* d_out, int out_size, void* d_ws, size_t ws_size,
                              hipStream_t stream) {
    const float* trg = (const float*)d_in[0];
    // d_in[1] = src: unused (n_layers = 0)
    const float* W1  = (const float*)d_in[2];
    const float* b1  = (const float*)d_in[3];
    const float* W2  = (const float*)d_in[4];
    const float* b2  = (const float*)d_in[5];
    float* out = (float*)d_out;

    // Workspace layout: m[B*NBLK] | l[B*NBLK] | pooled[B*NBLK*HID]
    float* ws_m = (float*)d_ws;
    float* ws_l = ws_m + BATCH * NBLK;
    float* ws_p = ws_l + BATCH * NBLK;

    pool_pass<<<dim3(BATCH * NBLK), THREADS, 0, stream>>>(trg, ws_m, ws_l, ws_p);
    finish_pass<<<dim3(BATCH), THREADS, 0, stream>>>(ws_m, ws_l, ws_p,
                                                     W1, b1, W2, b2, out);
}

// Round 8
// 55.303 us; speedup vs baseline: 1.1328x; 1.1328x over previous
//
#include <hip/hip_runtime.h>
#include <math.h>

#define BATCH 64
#define SEQ   4096
#define HID   256
#define NBLK  32                          // S-chunks per batch
#define ROWS_PER_BLK (SEQ / NBLK)         // 128 rows per block
#define THREADS 256
#define NWAVE (THREADS / 64)              // 4 waves
#define GSZ   8                           // lanes per row-group
#define NGRP  (THREADS / GSZ)             // 32 groups -> 32 rows per iter
#define ITERS (ROWS_PER_BLK / NGRP)       // 4 serial iterations (even)
#define VPL   (HID / (GSZ * 4))           // 8 float4 per lane per row

// Kernel 1: single streaming pass over trg with online softmax (defer-max).
// Each 8-lane group owns one row per iteration (8 float4/lane = 8 KB per
// wave-iteration, shuffle depth 3) + ping-pong prefetch -> maximizes bytes
// amortized per serial chain. Cross-group combine in-register (xor 8/16/32);
// LDS only 4.2 KB. No launch_bounds min-wave cap (R5 spill lesson).
__global__ __launch_bounds__(THREADS) void pool_pass(
        const float* __restrict__ trg,
        float* __restrict__ ws_m,
        float* __restrict__ ws_l,
        float* __restrict__ ws_p) {
    const int b     = blockIdx.x / NBLK;
    const int chunk = blockIdx.x % NBLK;
    const int tid   = threadIdx.x;
    const int wave  = tid >> 6;
    const int lane  = tid & 63;
    const int gid   = tid >> 3;           // block-level group id 0..31
    const int sub   = tid & 7;            // lane within group
    const int gw    = lane >> 3;          // group id within wave 0..7

    const float* base = trg + ((size_t)b * SEQ + (size_t)chunk * ROWS_PER_BLK) * HID
                      + (size_t)gid * HID + sub * 4;   // row gid, this lane's cols

    float m = -INFINITY, l = 0.f;
    float4 acc[VPL];
    #pragma unroll
    for (int q = 0; q < VPL; ++q) acc[q] = make_float4(0.f, 0.f, 0.f, 0.f);

    float4 v0[VPL], v1[VPL];

    #define LOADV(dst, t)                                                     \
        {                                                                     \
            const float* rp_ = base + (size_t)(t) * (NGRP * HID);             \
            _Pragma("unroll")                                                 \
            for (int q = 0; q < VPL; ++q)                                     \
                dst[q] = *reinterpret_cast<const float4*>(rp_ + q * (GSZ*4)); \
        }

    #define PROCESS(v)                                                        \
        {                                                                     \
            float ss = 0.f;                                                   \
            _Pragma("unroll")                                                 \
            for (int q = 0; q < VPL; ++q)                                     \
                ss += v[q].x * v[q].x + v[q].y * v[q].y                       \
                    + v[q].z * v[q].z + v[q].w * v[q].w;                      \
            ss += __shfl_xor(ss, 1, 64);                                      \
            ss += __shfl_xor(ss, 2, 64);                                      \
            ss += __shfl_xor(ss, 4, 64);                                      \
            const float nrm = sqrtf(ss);                                      \
            if (nrm > m + 8.f) {          /* defer-max: rare */               \
                const float sc_ = __expf(m - nrm);                            \
                l *= sc_;                                                     \
                _Pragma("unroll")                                             \
                for (int q = 0; q < VPL; ++q) {                               \
                    acc[q].x *= sc_; acc[q].y *= sc_;                         \
                    acc[q].z *= sc_; acc[q].w *= sc_;                         \
                }                                                             \
                m = nrm;                                                      \
            }                                                                 \
            const float p = __expf(nrm - m);   /* <= e^8 */                   \
            l += p;                                                           \
            _Pragma("unroll")                                                 \
            for (int q = 0; q < VPL; ++q) {                                   \
                acc[q].x = fmaf(p, v[q].x, acc[q].x);                         \
                acc[q].y = fmaf(p, v[q].y, acc[q].y);                         \
                acc[q].z = fmaf(p, v[q].z, acc[q].z);                         \
                acc[q].w = fmaf(p, v[q].w, acc[q].w);                         \
            }                                                                 \
        }

    LOADV(v0, 0)
    #pragma unroll
    for (int t = 0; t < ITERS; t += 2) {
        LOADV(v1, t + 1)                  // prefetch while v0 computes
        PROCESS(v0)
        if (t + 2 < ITERS) LOADV(v0, t + 2)
        PROCESS(v1)
    }
    #undef LOADV
    #undef PROCESS

    // ---- in-wave cross-group combine (masks 8/16/32 cross the 8 groups) ----
    float m_w = m;
    m_w = fmaxf(m_w, __shfl_xor(m_w, 8, 64));
    m_w = fmaxf(m_w, __shfl_xor(m_w, 16, 64));
    m_w = fmaxf(m_w, __shfl_xor(m_w, 32, 64));
    const float sc = __expf(m - m_w);     // group-uniform rescale to wave max
    float l_w = l * sc;
    l_w += __shfl_xor(l_w, 8, 64);
    l_w += __shfl_xor(l_w, 16, 64);
    l_w += __shfl_xor(l_w, 32, 64);
    #pragma unroll
    for (int q = 0; q < VPL; ++q) {
        float4 a = acc[q];
        a.x *= sc; a.y *= sc; a.z *= sc; a.w *= sc;
        a.x += __shfl_xor(a.x, 8, 64);
        a.y += __shfl_xor(a.y, 8, 64);
        a.z += __shfl_xor(a.z, 8, 64);
        a.w += __shfl_xor(a.w, 8, 64);
        a.x += __shfl_xor(a.x, 16, 64);
        a.y += __shfl_xor(a.y, 16, 64);
        a.z += __shfl_xor(a.z, 16, 64);
        a.w += __shfl_xor(a.w, 16, 64);
        a.x += __shfl_xor(a.x, 32, 64);
        a.y += __shfl_xor(a.y, 32, 64);
        a.z += __shfl_xor(a.z, 32, 64);
        a.w += __shfl_xor(a.w, 32, 64);
        acc[q] = a;                       // wave col-sums for cols q*32+sub*4
    }

    // static-index select: lane (gw,sub) keeps cols gw*32 + sub*4 .. +3
    float4 mine = acc[0];
    #pragma unroll
    for (int q = 1; q < VPL; ++q) if (gw == q) mine = acc[q];

    // ---- tiny cross-wave combine in LDS (4.2 KB) ----
    __shared__ float s_p[NWAVE][HID];
    __shared__ float s_m[NWAVE];
    __shared__ float s_l[NWAVE];
    *reinterpret_cast<float4*>(&s_p[wave][gw * 32 + sub * 4]) = mine;
    if (lane == 0) { s_m[wave] = m_w; s_l[wave] = l_w; }
    __syncthreads();

    const int j = tid;                    // output column 0..255
    const float m_blk = fmaxf(fmaxf(s_m[0], s_m[1]), fmaxf(s_m[2], s_m[3]));
    const float e0 = __expf(s_m[0] - m_blk);
    const float e1 = __expf(s_m[1] - m_blk);
    const float e2 = __expf(s_m[2] - m_blk);
    const float e3 = __expf(s_m[3] - m_blk);
    const float pj = e0 * s_p[0][j] + e1 * s_p[1][j]
                   + e2 * s_p[2][j] + e3 * s_p[3][j];
    const int pidx = b * NBLK + chunk;
    ws_p[(size_t)pidx * HID + j] = pj;
    if (j == 0) {
        ws_m[pidx] = m_blk;
        ws_l[pidx] = e0 * s_l[0] + e1 * s_l[1] + e2 * s_l[2] + e3 * s_l[3];
    }
}

// Kernel 2: combine NBLK partials per batch, normalize, tiny MLP.
__global__ __launch_bounds__(THREADS) void finish_pass(
        const float* __restrict__ ws_m,
        const float* __restrict__ ws_l,
        const float* __restrict__ ws_p,
        const float* __restrict__ W1,
        const float* __restrict__ b1,
        const float* __restrict__ W2,
        const float* __restrict__ b2,
        float* __restrict__ out) {
    const int b = blockIdx.x;
    const int j = threadIdx.x;  // 0..255: owns pooled[j], h[j]

    __shared__ float s_m[NBLK];
    __shared__ float s_l[NBLK];
    __shared__ float s_scale[NBLK];
    __shared__ float s_pooled[HID];
    __shared__ float s_red[NWAVE];

    if (j < NBLK) {
        s_m[j] = ws_m[b * NBLK + j];
        s_l[j] = ws_l[b * NBLK + j];
    }
    __syncthreads();

    float m = s_m[0];
    #pragma unroll
    for (int i = 1; i < NBLK; ++i) m = fmaxf(m, s_m[i]);
    if (j < NBLK) s_scale[j] = __expf(s_m[j] - m);
    __syncthreads();

    float l = 0.f, pj = 0.f;
    #pragma unroll 8
    for (int i = 0; i < NBLK; ++i) {
        l  = fmaf(s_l[i], s_scale[i], l);
        pj = fmaf(ws_p[(size_t)(b * NBLK + i) * HID + j], s_scale[i], pj);
    }
    s_pooled[j] = pj / l;
    __syncthreads();

    // FC1 column j: h = relu(sum_k pooled[k] * W1[k][j] + b1[j])
    float h = b1[j];
    #pragma unroll 16
    for (int k = 0; k < HID; ++k)
        h = fmaf(s_pooled[k], W1[k * HID + j], h);
    h = fmaxf(h, 0.f);

    // FC2: out[b] = sum_j h[j] * W2[j] + b2
    float v = h * W2[j];
    #pragma unroll
    for (int off = 32; off > 0; off >>= 1)
        v += __shfl_xor(v, off, 64);
    if ((j & 63) == 0) s_red[j >> 6] = v;
    __syncthreads();
    if (j == 0)
        out[b] = s_red[0] + s_red[1] + s_red[2] + s_red[3] + b2[0];
}

extern "C" void kernel_launch(void* const* d_in, const int* in_sizes, int n_in,
                              void* d_out, int out_size, void* d_ws, size_t ws_size,
                              hipStream_t stream) {
    const float* trg = (const float*)d_in[0];
    // d_in[1] = src: unused (n_layers = 0)
    const float* W1  = (const float*)d_in[2];
    const float* b1  = (const float*)d_in[3];
    const float* W2  = (const float*)d_in[4];
    const float* b2  = (const float*)d_in[5];
    float* out = (float*)d_out;

    // Workspace layout: m[B*NBLK] | l[B*NBLK] | pooled[B*NBLK*HID]
    float* ws_m = (float*)d_ws;
    float* ws_l = ws_m + BATCH * NBLK;
    float* ws_p = ws_l + BATCH * NBLK;

    pool_pass<<<dim3(BATCH * NBLK), THREADS, 0, stream>>>(trg, ws_m, ws_l, ws_p);
    finish_pass<<<dim3(BATCH), THREADS, 0, stream>>>(ws_m, ws_l, ws_p,
                                                     W1, b1, W2, b2, out);
}

// Round 9
// 51.622 us; speedup vs baseline: 1.2136x; 1.0713x over previous
//
#include <hip/hip_runtime.h>
#include <math.h>

#define BATCH 64
#define SEQ   4096
#define HID   256
#define NBLK  16                          // S-chunks per batch
#define ROWS_PER_BLK (SEQ / NBLK)         // 256 rows per block
#define THREADS 256
#define NWAVE (THREADS / 64)              // 4 waves
#define GSZ   16                          // lanes per row-group
#define NGRP  (THREADS / GSZ)             // 16 groups -> 16 rows per iter
#define ITERS (ROWS_PER_BLK / NGRP)       // 16 serial iterations (even)
#define VPL   (HID / (GSZ * 4))           // 4 vec4 per lane per row

typedef float f4 __attribute__((ext_vector_type(4)));

// Kernel 1: single streaming pass over trg with online softmax (defer-max).
// R6 structure (best so far): 16-lane row-groups, ping-pong prefetch,
// in-register cross-group combine, 4.2 KB LDS. New: NON-TEMPORAL loads
// (trg is touched exactly once -> skip cache allocation) and NBLK=16 so the
// 1024-block grid is a single co-resident round (4 blocks/CU at ~75 VGPR).
__global__ __launch_bounds__(THREADS) void pool_pass(
        const float* __restrict__ trg,
        float* __restrict__ ws_m,
        float* __restrict__ ws_l,
        float* __restrict__ ws_p) {
    const int b     = blockIdx.x / NBLK;
    const int chunk = blockIdx.x % NBLK;
    const int tid   = threadIdx.x;
    const int wave  = tid >> 6;
    const int lane  = tid & 63;
    const int gid   = tid >> 4;           // block-level group id 0..15
    const int sub   = tid & 15;           // lane within group
    const int gw    = gid & 3;            // group id within wave 0..3

    const float* base = trg + ((size_t)b * SEQ + (size_t)chunk * ROWS_PER_BLK) * HID
                      + (size_t)gid * HID + sub * 4;   // row gid, this lane's cols

    float m = -INFINITY, l = 0.f;
    f4 acc[VPL];
    #pragma unroll
    for (int q = 0; q < VPL; ++q) acc[q] = (f4)0.f;

    f4 v0[VPL], v1[VPL];

    #define LOADV(dst, t)                                                     \
        {                                                                     \
            const float* rp_ = base + (size_t)(t) * (NGRP * HID);             \
            _Pragma("unroll")                                                 \
            for (int q = 0; q < VPL; ++q)                                     \
                dst[q] = __builtin_nontemporal_load(                          \
                    reinterpret_cast<const f4*>(rp_ + q * (GSZ * 4)));        \
        }

    #define PROCESS(v)                                                        \
        {                                                                     \
            f4 sq = v[0] * v[0];                                              \
            _Pragma("unroll")                                                 \
            for (int q = 1; q < VPL; ++q) sq += v[q] * v[q];                  \
            float ss = sq.x + sq.y + sq.z + sq.w;                             \
            ss += __shfl_xor(ss, 1, 64);                                      \
            ss += __shfl_xor(ss, 2, 64);                                      \
            ss += __shfl_xor(ss, 4, 64);                                      \
            ss += __shfl_xor(ss, 8, 64);                                      \
            const float nrm = sqrtf(ss);                                      \
            if (nrm > m + 8.f) {          /* defer-max: rare */               \
                const float sc_ = __expf(m - nrm);                            \
                l *= sc_;                                                     \
                _Pragma("unroll")                                             \
                for (int q = 0; q < VPL; ++q) acc[q] *= sc_;                  \
                m = nrm;                                                      \
            }                                                                 \
            const float p = __expf(nrm - m);   /* <= e^8 */                   \
            l += p;                                                           \
            _Pragma("unroll")                                                 \
            for (int q = 0; q < VPL; ++q) acc[q] += p * v[q];                 \
        }

    LOADV(v0, 0)
    #pragma unroll 1                      // tight ping-pong loop
    for (int t = 0; t < ITERS; t += 2) {
        LOADV(v1, t + 1)                  // prefetch while v0 computes
        PROCESS(v0)
        if (t + 2 < ITERS) LOADV(v0, t + 2)
        PROCESS(v1)
    }
    #undef LOADV
    #undef PROCESS

    // ---- in-wave cross-group combine (masks 16/32 cross the 4 groups) ----
    float m_w = m;
    m_w = fmaxf(m_w, __shfl_xor(m_w, 16, 64));
    m_w = fmaxf(m_w, __shfl_xor(m_w, 32, 64));
    const float sc = __expf(m - m_w);     // group-uniform rescale to wave max
    float l_w = l * sc;
    l_w += __shfl_xor(l_w, 16, 64);
    l_w += __shfl_xor(l_w, 32, 64);
    #pragma unroll
    for (int q = 0; q < VPL; ++q) {
        f4 a = acc[q] * sc;
        a.x += __shfl_xor(a.x, 16, 64);
        a.y += __shfl_xor(a.y, 16, 64);
        a.z += __shfl_xor(a.z, 16, 64);
        a.w += __shfl_xor(a.w, 16, 64);
        a.x += __shfl_xor(a.x, 32, 64);
        a.y += __shfl_xor(a.y, 32, 64);
        a.z += __shfl_xor(a.z, 32, 64);
        a.w += __shfl_xor(a.w, 32, 64);
        acc[q] = a;                       // wave col-sums for cols q*64+sub*4
    }

    // static-index select: lane (gw,sub) keeps cols gw*64 + sub*4 .. +3
    f4 mine = acc[0];
    #pragma unroll
    for (int q = 1; q < VPL; ++q) if (gw == q) mine = acc[q];

    // ---- tiny cross-wave combine in LDS (4.2 KB) ----
    __shared__ float s_p[NWAVE][HID];
    __shared__ float s_m[NWAVE];
    __shared__ float s_l[NWAVE];
    *reinterpret_cast<f4*>(&s_p[wave][gw * 64 + sub * 4]) = mine;
    if (lane == 0) { s_m[wave] = m_w; s_l[wave] = l_w; }
    __syncthreads();

    const int j = tid;                    // output column 0..255
    const float m_blk = fmaxf(fmaxf(s_m[0], s_m[1]), fmaxf(s_m[2], s_m[3]));
    const float e0 = __expf(s_m[0] - m_blk);
    const float e1 = __expf(s_m[1] - m_blk);
    const float e2 = __expf(s_m[2] - m_blk);
    const float e3 = __expf(s_m[3] - m_blk);
    const float pj = e0 * s_p[0][j] + e1 * s_p[1][j]
                   + e2 * s_p[2][j] + e3 * s_p[3][j];
    const int pidx = b * NBLK + chunk;
    ws_p[(size_t)pidx * HID + j] = pj;
    if (j == 0) {
        ws_m[pidx] = m_blk;
        ws_l[pidx] = e0 * s_l[0] + e1 * s_l[1] + e2 * s_l[2] + e3 * s_l[3];
    }
}

// Kernel 2: combine NBLK partials per batch, normalize, tiny MLP.
__global__ __launch_bounds__(THREADS) void finish_pass(
        const float* __restrict__ ws_m,
        const float* __restrict__ ws_l,
        const float* __restrict__ ws_p,
        const float* __restrict__ W1,
        const float* __restrict__ b1,
        const float* __restrict__ W2,
        const float* __restrict__ b2,
        float* __restrict__ out) {
    const int b = blockIdx.x;
    const int j = threadIdx.x;  // 0..255: owns pooled[j], h[j]

    __shared__ float s_m[NBLK];
    __shared__ float s_l[NBLK];
    __shared__ float s_scale[NBLK];
    __shared__ float s_pooled[HID];
    __shared__ float s_red[NWAVE];

    if (j < NBLK) {
        s_m[j] = ws_m[b * NBLK + j];
        s_l[j] = ws_l[b * NBLK + j];
    }
    __syncthreads();

    float m = s_m[0];
    #pragma unroll
    for (int i = 1; i < NBLK; ++i) m = fmaxf(m, s_m[i]);
    if (j < NBLK) s_scale[j] = __expf(s_m[j] - m);
    __syncthreads();

    float l = 0.f, pj = 0.f;
    #pragma unroll 8
    for (int i = 0; i < NBLK; ++i) {
        l  = fmaf(s_l[i], s_scale[i], l);
        pj = fmaf(ws_p[(size_t)(b * NBLK + i) * HID + j], s_scale[i], pj);
    }
    s_pooled[j] = pj / l;
    __syncthreads();

    // FC1 column j: h = relu(sum_k pooled[k] * W1[k][j] + b1[j])
    float h = b1[j];
    #pragma unroll 16
    for (int k = 0; k < HID; ++k)
        h = fmaf(s_pooled[k], W1[k * HID + j], h);
    h = fmaxf(h, 0.f);

    // FC2: out[b] = sum_j h[j] * W2[j] + b2
    float v = h * W2[j];
    #pragma unroll
    for (int off = 32; off > 0; off >>= 1)
        v += __shfl_xor(v, off, 64);
    if ((j & 63) == 0) s_red[j >> 6] = v;
    __syncthreads();
    if (j == 0)
        out[b] = s_red[0] + s_red[1] + s_red[2] + s_red[3] + b2[0];
}

extern "C" void kernel_launch(void* const* d_in, const int* in_sizes, int n_in,
                              void* d_out, int out_size, void* d_ws, size_t ws_size,
                              hipStream_t stream) {
    const float* trg = (const float*)d_in[0];
    // d_in[1] = src: unused (n_layers = 0)
    const float* W1  = (const float*)d_in[2];
    const float* b1  = (const float*)d_in[3];
    const float* W2  = (const float*)d_in[4];
    const float* b2  = (const float*)d_in[5];
    float* out = (float*)d_out;

    // Workspace layout: m[B*NBLK] | l[B*NBLK] | pooled[B*NBLK*HID]
    float* ws_m = (float*)d_ws;
    float* ws_l = ws_m + BATCH * NBLK;
    float* ws_p = ws_l + BATCH * NBLK;

    pool_pass<<<dim3(BATCH * NBLK), THREADS, 0, stream>>>(trg, ws_m, ws_l, ws_p);
    finish_pass<<<dim3(BATCH), THREADS, 0, stream>>>(ws_m, ws_l, ws_p,
                                                     W1, b1, W2, b2, out);
}